// Round 1
// baseline (190.143 us; speedup 1.0000x reference)
//
#include <hip/hip_runtime.h>
#include <math.h>

#define NB 32      // B
#define NV 1024    // V
#define NFT 16     // F
#define NA 32      // A
#define NP 64      // P
#define NOUT 128   // NF
#define NC 96      // C = P + A
#define NC2 192    // 2C

// ---------------------------------------------------------------------------
// K1: f[b,v,0:64] = x@W_flr + b_flr ; f[b,v,64+a] = exp(-(x@W_s + b_s)^2)
// one thread per output element of f (B*V*96 threads)
// ---------------------------------------------------------------------------
__global__ void k1_vertex(const float* __restrict__ x,
                          const float* __restrict__ W_flr,
                          const float* __restrict__ b_flr,
                          const float* __restrict__ W_s,
                          const float* __restrict__ b_s,
                          float* __restrict__ fbuf) {
    int t = blockIdx.x * blockDim.x + threadIdx.x;
    // t = (b*V + v)*96 + j
    int j = t % NC;
    int row = t / NC;          // b*V + v
    const float* xr = x + row * NFT;

    float acc;
    if (j < NP) {
        acc = b_flr[j];
#pragma unroll
        for (int k = 0; k < NFT; ++k)
            acc = fmaf(xr[k], W_flr[k * NP + j], acc);
        fbuf[t] = acc;
    } else {
        int a = j - NP;
        acc = b_s[a];
#pragma unroll
        for (int k = 0; k < NFT; ++k)
            acc = fmaf(xr[k], W_s[k * NA + a], acc);
        fbuf[t] = __expf(-acc * acc) ;
    }
}

// ---------------------------------------------------------------------------
// K2: per batch b, per a-group of 8:
//   agg_max[b,a,c]  = max_v  ew[b,v,a]*f[b,v,c]
//   agg_mean[b,a,c] = (1/V) sum_v ew[b,v,a]*f[b,v,c]
// agg layout: agg[((b*A + a)*192) + c] = max,  ... + 96 + c = mean
// grid (B, 4), 256 threads, each thread owns 3 (a_local,c) pairs
// ---------------------------------------------------------------------------
#define VSTAGE 16
__global__ void k2_agg(const float* __restrict__ fbuf,
                       float* __restrict__ agg) {
    __shared__ float lds[VSTAGE * NC];   // 16 rows x 96 cols = 6 KB
    int b  = blockIdx.x;
    int ag = blockIdx.y;                 // a-group: a = ag*8 + a_local
    int tid = threadIdx.x;

    int p0 = tid, p1 = tid + 256, p2 = tid + 512;     // pair ids < 768
    int a0 = p0 / NC, c0 = p0 % NC;
    int a1 = p1 / NC, c1 = p1 % NC;
    int a2 = p2 / NC, c2 = p2 % NC;

    float s0 = 0.f, s1 = 0.f, s2 = 0.f;
    float m0 = -INFINITY, m1 = -INFINITY, m2 = -INFINITY;

    const float* fb = fbuf + (size_t)b * NV * NC;

    for (int v0 = 0; v0 < NV; v0 += VSTAGE) {
        __syncthreads();
        // stage 16 rows (1536 floats) coalesced
        const float* src = fb + v0 * NC;
#pragma unroll
        for (int l = tid; l < VSTAGE * NC; l += 256)
            lds[l] = src[l];
        __syncthreads();
#pragma unroll
        for (int r = 0; r < VSTAGE; ++r) {
            const float* rowp = lds + r * NC;
            float e0 = rowp[NP + (ag * 8 + a0)];
            float e1 = rowp[NP + (ag * 8 + a1)];
            float e2 = rowp[NP + (ag * 8 + a2)];
            float pr0 = e0 * rowp[c0];
            float pr1 = e1 * rowp[c1];
            float pr2 = e2 * rowp[c2];
            s0 += pr0; s1 += pr1; s2 += pr2;
            m0 = fmaxf(m0, pr0); m1 = fmaxf(m1, pr1); m2 = fmaxf(m2, pr2);
        }
    }

    const float inv_v = 1.0f / (float)NV;
    float* ab = agg + ((size_t)b * NA) * NC2;
    int aa0 = ag * 8 + a0, aa1 = ag * 8 + a1, aa2 = ag * 8 + a2;
    ab[aa0 * NC2 + c0]      = m0;
    ab[aa0 * NC2 + NC + c0] = s0 * inv_v;
    ab[aa1 * NC2 + c1]      = m1;
    ab[aa1 * NC2 + NC + c1] = s1 * inv_v;
    ab[aa2 * NC2 + c2]      = m2;
    ab[aa2 * NC2 + NC + c2] = s2 * inv_v;
}

// ---------------------------------------------------------------------------
// K3: Gp[b,a,n] = W_out[(6160+a)*128 + n] + sum_c agg[b,a,c]*W_out[(16+a*192+c)*128+n]
// one thread per (b,a,n): B*A*128 = 131072 threads
// ---------------------------------------------------------------------------
__global__ void k3_G(const float* __restrict__ agg,
                     const float* __restrict__ W_out,
                     float* __restrict__ Gp) {
    int t = blockIdx.x * blockDim.x + threadIdx.x;   // (b*A + a)*128 + n
    int n = t % NOUT;
    int ba = t / NOUT;          // b*A + a
    int a = ba % NA;

    const float* ar = agg + (size_t)ba * NC2;
    const float* wr = W_out + (size_t)(NFT + a * NC2) * NOUT + n;
    float acc = W_out[(size_t)(NFT + NA * NC2 + a) * NOUT + n];  // tail row 6160+a
#pragma unroll 8
    for (int c = 0; c < NC2; ++c)
        acc = fmaf(ar[c], wr[(size_t)c * NOUT], acc);
    Gp[t] = acc;
}

// ---------------------------------------------------------------------------
// K4: out[b,v,n] = tanh( b_out[n] + sum_k x[b,v,k]*W_out[k*128+n]
//                        + sum_a ew[b,v,a]*Gp[b,a,n] )
// one thread per output: B*V*128 = 4.19M threads
// ---------------------------------------------------------------------------
__global__ void k4_out(const float* __restrict__ x,
                       const float* __restrict__ fbuf,
                       const float* __restrict__ Gp,
                       const float* __restrict__ W_out,
                       const float* __restrict__ b_out,
                       float* __restrict__ out) {
    int t = blockIdx.x * blockDim.x + threadIdx.x;   // (b*V + v)*128 + n
    int n = t % NOUT;
    int row = t / NOUT;          // b*V + v
    int b = row / NV;

    float s = b_out[n];
    const float* xr = x + (size_t)row * NFT;
#pragma unroll
    for (int k = 0; k < NFT; ++k)
        s = fmaf(xr[k], W_out[(size_t)k * NOUT + n], s);

    const float* ewr = fbuf + (size_t)row * NC + NP;
    const float* gp = Gp + ((size_t)b * NA) * NOUT + n;
#pragma unroll
    for (int a = 0; a < NA; ++a)
        s = fmaf(ewr[a], gp[(size_t)a * NOUT], s);

    out[t] = tanhf(s);
}

// ---------------------------------------------------------------------------
extern "C" void kernel_launch(void* const* d_in, const int* in_sizes, int n_in,
                              void* d_out, int out_size, void* d_ws, size_t ws_size,
                              hipStream_t stream) {
    const float* x     = (const float*)d_in[0];
    const float* W_flr = (const float*)d_in[1];
    const float* b_flr = (const float*)d_in[2];
    const float* W_s   = (const float*)d_in[3];
    const float* b_s   = (const float*)d_in[4];
    const float* W_out = (const float*)d_in[5];
    const float* b_out = (const float*)d_in[6];
    float* out = (float*)d_out;

    // workspace layout (floats)
    float* fbuf = (float*)d_ws;                         // B*V*96   = 3,145,728
    float* agg  = fbuf + (size_t)NB * NV * NC;          // B*A*192  =   196,608
    float* Gp   = agg  + (size_t)NB * NA * NC2;         // B*A*128  =   131,072

    // K1: B*V*96 = 3,145,728 threads
    {
        int n = NB * NV * NC;
        k1_vertex<<<n / 256, 256, 0, stream>>>(x, W_flr, b_flr, W_s, b_s, fbuf);
    }
    // K2: grid (B, 4) x 256
    {
        dim3 g(NB, NA / 8);
        k2_agg<<<g, 256, 0, stream>>>(fbuf, agg);
    }
    // K3: B*A*128 = 131,072 threads
    {
        int n = NB * NA * NOUT;
        k3_G<<<n / 256, 256, 0, stream>>>(agg, W_out, Gp);
    }
    // K4: B*V*128 = 4,194,304 threads
    {
        int n = NB * NV * NOUT;
        k4_out<<<n / 256, 256, 0, stream>>>(x, fbuf, Gp, W_out, b_out, out);
    }
}

// Round 2
// 108.610 us; speedup vs baseline: 1.7507x; 1.7507x over previous
//
#include <hip/hip_runtime.h>
#include <math.h>

#define NB 32      // B
#define NV 1024    // V
#define NFT 16     // F
#define NA 32      // A
#define NP 64      // P
#define NOUT 128   // NF
#define NC 96      // C = P + A
#define NC2 192    // 2C

#define NSPLIT 16            // V-dimension splits for k2
#define VPB (NV / NSPLIT)    // 64 rows per block
#define NPAIR 768            // 8 a_local * 96 c
#define PARTSTRIDE (2 * NPAIR)  // max block then sum block

// ---------------------------------------------------------------------------
// K1: f[b,v,0:64] = x@W_flr + b_flr ; f[b,v,64+a] = exp(-(x@W_s + b_s)^2)
// ---------------------------------------------------------------------------
__global__ void k1_vertex(const float* __restrict__ x,
                          const float* __restrict__ W_flr,
                          const float* __restrict__ b_flr,
                          const float* __restrict__ W_s,
                          const float* __restrict__ b_s,
                          float* __restrict__ fbuf) {
    int t = blockIdx.x * blockDim.x + threadIdx.x;
    int j = t % NC;
    int row = t / NC;          // b*V + v
    const float* xr = x + row * NFT;

    float acc;
    if (j < NP) {
        acc = b_flr[j];
#pragma unroll
        for (int k = 0; k < NFT; ++k)
            acc = fmaf(xr[k], W_flr[k * NP + j], acc);
        fbuf[t] = acc;
    } else {
        int a = j - NP;
        acc = b_s[a];
#pragma unroll
        for (int k = 0; k < NFT; ++k)
            acc = fmaf(xr[k], W_s[k * NA + a], acc);
        fbuf[t] = __expf(-acc * acc);
    }
}

// ---------------------------------------------------------------------------
// K2a: partial reduction over a 64-row V-slice.
// grid (B, 4, NSPLIT); block 256. Each thread owns 3 (a_local,c) pairs.
// part[((b*4+ag)*NSPLIT+vs)*1536 + pair] = partial max ; +768 = partial sum
// ---------------------------------------------------------------------------
#define VSTAGE 16
__global__ void k2_part(const float* __restrict__ fbuf,
                        float* __restrict__ part) {
    __shared__ float lds[VSTAGE * NC];   // 6 KB
    int b  = blockIdx.x;
    int ag = blockIdx.y;
    int vs = blockIdx.z;
    int tid = threadIdx.x;

    int p0 = tid, p1 = tid + 256, p2 = tid + 512;
    int a0 = p0 / NC, c0 = p0 % NC;
    int a1 = p1 / NC, c1 = p1 % NC;
    int a2 = p2 / NC, c2 = p2 % NC;
    int ea0 = NP + ag * 8 + a0, ea1 = NP + ag * 8 + a1, ea2 = NP + ag * 8 + a2;

    float s0 = 0.f, s1 = 0.f, s2 = 0.f;
    float m0 = -INFINITY, m1 = -INFINITY, m2 = -INFINITY;

    const float* fb = fbuf + ((size_t)b * NV + vs * VPB) * NC;

    for (int v0 = 0; v0 < VPB; v0 += VSTAGE) {
        __syncthreads();
        const float* src = fb + v0 * NC;
#pragma unroll
        for (int l = tid; l < VSTAGE * NC; l += 256)
            lds[l] = src[l];
        __syncthreads();
#pragma unroll
        for (int r = 0; r < VSTAGE; ++r) {
            const float* rowp = lds + r * NC;
            float e0 = rowp[ea0];
            float e1 = rowp[ea1];
            float e2 = rowp[ea2];
            float pr0 = e0 * rowp[c0];
            float pr1 = e1 * rowp[c1];
            float pr2 = e2 * rowp[c2];
            s0 += pr0; s1 += pr1; s2 += pr2;
            m0 = fmaxf(m0, pr0); m1 = fmaxf(m1, pr1); m2 = fmaxf(m2, pr2);
        }
    }

    float* pb = part + (size_t)((b * 4 + ag) * NSPLIT + vs) * PARTSTRIDE;
    pb[p0] = m0;          pb[p1] = m1;          pb[p2] = m2;
    pb[NPAIR + p0] = s0;  pb[NPAIR + p1] = s1;  pb[NPAIR + p2] = s2;
}

// ---------------------------------------------------------------------------
// K2b: combine NSPLIT partials.
// one thread per (b, ag, pair): B*4*768 = 98304 threads.
// agg[(b*A + a)*192 + c] = max ; + 96 + c = mean
// ---------------------------------------------------------------------------
__global__ void k2_comb(const float* __restrict__ part,
                        float* __restrict__ agg) {
    int t = blockIdx.x * blockDim.x + threadIdx.x;   // (b*4+ag)*768 + pair
    int pair = t % NPAIR;
    int bg = t / NPAIR;            // b*4 + ag
    int a_local = pair / NC, c = pair % NC;

    const float* pb = part + (size_t)bg * NSPLIT * PARTSTRIDE;
    float m = -INFINITY, s = 0.f;
#pragma unroll
    for (int vs = 0; vs < NSPLIT; ++vs) {
        m = fmaxf(m, pb[vs * PARTSTRIDE + pair]);
        s += pb[vs * PARTSTRIDE + NPAIR + pair];
    }

    int b = bg / 4, ag = bg % 4;
    int a = ag * 8 + a_local;
    float* ab = agg + ((size_t)b * NA + a) * NC2;
    ab[c] = m;
    ab[NC + c] = s * (1.0f / (float)NV);
}

// ---------------------------------------------------------------------------
// K3: Gp[b,a,n] = W_out[(6160+a)*128+n] + sum_c agg[b,a,c]*W_out[(16+a*192+c)*128+n]
// ---------------------------------------------------------------------------
__global__ void k3_G(const float* __restrict__ agg,
                     const float* __restrict__ W_out,
                     float* __restrict__ Gp) {
    int t = blockIdx.x * blockDim.x + threadIdx.x;
    int n = t % NOUT;
    int ba = t / NOUT;
    int a = ba % NA;

    const float* ar = agg + (size_t)ba * NC2;
    const float* wr = W_out + (size_t)(NFT + a * NC2) * NOUT + n;
    float acc = W_out[(size_t)(NFT + NA * NC2 + a) * NOUT + n];
#pragma unroll 8
    for (int c = 0; c < NC2; ++c)
        acc = fmaf(ar[c], wr[(size_t)c * NOUT], acc);
    Gp[t] = acc;
}

// ---------------------------------------------------------------------------
// K4: out[b,v,n] = tanh( b_out[n] + sum_k x[b,v,k]*W_out[k*128+n]
//                        + sum_a ew[b,v,a]*Gp[b,a,n] )
// ---------------------------------------------------------------------------
__global__ void k4_out(const float* __restrict__ x,
                       const float* __restrict__ fbuf,
                       const float* __restrict__ Gp,
                       const float* __restrict__ W_out,
                       const float* __restrict__ b_out,
                       float* __restrict__ out) {
    int t = blockIdx.x * blockDim.x + threadIdx.x;
    int n = t % NOUT;
    int row = t / NOUT;
    int b = row / NV;

    float s = b_out[n];
    const float* xr = x + (size_t)row * NFT;
#pragma unroll
    for (int k = 0; k < NFT; ++k)
        s = fmaf(xr[k], W_out[(size_t)k * NOUT + n], s);

    const float* ewr = fbuf + (size_t)row * NC + NP;
    const float* gp = Gp + ((size_t)b * NA) * NOUT + n;
#pragma unroll
    for (int a = 0; a < NA; ++a)
        s = fmaf(ewr[a], gp[(size_t)a * NOUT], s);

    out[t] = tanhf(s);
}

// ---------------------------------------------------------------------------
extern "C" void kernel_launch(void* const* d_in, const int* in_sizes, int n_in,
                              void* d_out, int out_size, void* d_ws, size_t ws_size,
                              hipStream_t stream) {
    const float* x     = (const float*)d_in[0];
    const float* W_flr = (const float*)d_in[1];
    const float* b_flr = (const float*)d_in[2];
    const float* W_s   = (const float*)d_in[3];
    const float* b_s   = (const float*)d_in[4];
    const float* W_out = (const float*)d_in[5];
    const float* b_out = (const float*)d_in[6];
    float* out = (float*)d_out;

    // workspace layout (floats)
    float* fbuf = (float*)d_ws;                         // B*V*96        = 3,145,728
    float* agg  = fbuf + (size_t)NB * NV * NC;          // B*A*192       =   196,608
    float* Gp   = agg  + (size_t)NB * NA * NC2;         // B*A*128       =   131,072
    float* part = Gp   + (size_t)NB * NA * NOUT;        // 2048*1536     = 3,145,728

    // K1
    {
        int n = NB * NV * NC;
        k1_vertex<<<n / 256, 256, 0, stream>>>(x, W_flr, b_flr, W_s, b_s, fbuf);
    }
    // K2a: grid (B, 4, 16) x 256 = 2048 blocks
    {
        dim3 g(NB, NA / 8, NSPLIT);
        k2_part<<<g, 256, 0, stream>>>(fbuf, part);
    }
    // K2b: 98304 threads
    {
        int n = NB * 4 * NPAIR;
        k2_comb<<<n / 256, 256, 0, stream>>>(part, agg);
    }
    // K3
    {
        int n = NB * NA * NOUT;
        k3_G<<<n / 256, 256, 0, stream>>>(agg, W_out, Gp);
    }
    // K4
    {
        int n = NB * NV * NOUT;
        k4_out<<<n / 256, 256, 0, stream>>>(x, fbuf, Gp, W_out, b_out, out);
    }
}

// Round 3
// 75.358 us; speedup vs baseline: 2.5232x; 1.4413x over previous
//
#include <hip/hip_runtime.h>
#include <math.h>

#define NB 32      // B
#define NV 1024    // V
#define NFT 16     // F
#define NA 32      // A
#define NP 64      // P
#define NOUT 128   // NF
#define NC 96      // C = P + A
#define NC2 192    // 2C

#define NSPLIT 16            // V-dimension splits for k2
#define VPB (NV / NSPLIT)    // 64 rows per block
#define NPAIR 768            // 8 a_local * 96 c
#define PARTSTRIDE (2 * NPAIR)  // max block then sum block

// ---------------------------------------------------------------------------
// K1: f[b,v,0:64] = x@W_flr + b_flr ; f[b,v,64+a] = exp(-(x@W_s + b_s)^2)
// ---------------------------------------------------------------------------
__global__ void k1_vertex(const float* __restrict__ x,
                          const float* __restrict__ W_flr,
                          const float* __restrict__ b_flr,
                          const float* __restrict__ W_s,
                          const float* __restrict__ b_s,
                          float* __restrict__ fbuf) {
    int t = blockIdx.x * blockDim.x + threadIdx.x;
    int j = t % NC;
    int row = t / NC;          // b*V + v
    const float* xr = x + row * NFT;

    float acc;
    if (j < NP) {
        acc = b_flr[j];
#pragma unroll
        for (int k = 0; k < NFT; ++k)
            acc = fmaf(xr[k], W_flr[k * NP + j], acc);
        fbuf[t] = acc;
    } else {
        int a = j - NP;
        acc = b_s[a];
#pragma unroll
        for (int k = 0; k < NFT; ++k)
            acc = fmaf(xr[k], W_s[k * NA + a], acc);
        fbuf[t] = __expf(-acc * acc);
    }
}

// ---------------------------------------------------------------------------
// K2a: partial reduction over a 64-row V-slice.
// grid (B, 4, NSPLIT); block 256. Each thread owns 3 (a_local,c) pairs.
// ---------------------------------------------------------------------------
#define VSTAGE 16
__global__ void k2_part(const float* __restrict__ fbuf,
                        float* __restrict__ part) {
    __shared__ float lds[VSTAGE * NC];   // 6 KB
    int b  = blockIdx.x;
    int ag = blockIdx.y;
    int vs = blockIdx.z;
    int tid = threadIdx.x;

    int p0 = tid, p1 = tid + 256, p2 = tid + 512;
    int a0 = p0 / NC, c0 = p0 % NC;
    int a1 = p1 / NC, c1 = p1 % NC;
    int a2 = p2 / NC, c2 = p2 % NC;
    int ea0 = NP + ag * 8 + a0, ea1 = NP + ag * 8 + a1, ea2 = NP + ag * 8 + a2;

    float s0 = 0.f, s1 = 0.f, s2 = 0.f;
    float m0 = -INFINITY, m1 = -INFINITY, m2 = -INFINITY;

    const float* fb = fbuf + ((size_t)b * NV + vs * VPB) * NC;

    for (int v0 = 0; v0 < VPB; v0 += VSTAGE) {
        __syncthreads();
        const float* src = fb + v0 * NC;
#pragma unroll
        for (int l = tid; l < VSTAGE * NC; l += 256)
            lds[l] = src[l];
        __syncthreads();
#pragma unroll
        for (int r = 0; r < VSTAGE; ++r) {
            const float* rowp = lds + r * NC;
            float e0 = rowp[ea0];
            float e1 = rowp[ea1];
            float e2 = rowp[ea2];
            float pr0 = e0 * rowp[c0];
            float pr1 = e1 * rowp[c1];
            float pr2 = e2 * rowp[c2];
            s0 += pr0; s1 += pr1; s2 += pr2;
            m0 = fmaxf(m0, pr0); m1 = fmaxf(m1, pr1); m2 = fmaxf(m2, pr2);
        }
    }

    float* pb = part + (size_t)((b * 4 + ag) * NSPLIT + vs) * PARTSTRIDE;
    pb[p0] = m0;          pb[p1] = m1;          pb[p2] = m2;
    pb[NPAIR + p0] = s0;  pb[NPAIR + p1] = s1;  pb[NPAIR + p2] = s2;
}

// ---------------------------------------------------------------------------
// K2b: combine NSPLIT partials.
// ---------------------------------------------------------------------------
__global__ void k2_comb(const float* __restrict__ part,
                        float* __restrict__ agg) {
    int t = blockIdx.x * blockDim.x + threadIdx.x;   // (b*4+ag)*768 + pair
    int pair = t % NPAIR;
    int bg = t / NPAIR;            // b*4 + ag
    int a_local = pair / NC, c = pair % NC;

    const float* pb = part + (size_t)bg * NSPLIT * PARTSTRIDE;
    float m = -INFINITY, s = 0.f;
#pragma unroll
    for (int vs = 0; vs < NSPLIT; ++vs) {
        m = fmaxf(m, pb[vs * PARTSTRIDE + pair]);
        s += pb[vs * PARTSTRIDE + NPAIR + pair];
    }

    int b = bg / 4, ag = bg % 4;
    int a = ag * 8 + a_local;
    float* ab = agg + ((size_t)b * NA + a) * NC2;
    ab[c] = m;
    ab[NC + c] = s * (1.0f / (float)NV);
}

// ---------------------------------------------------------------------------
// K3: Gp[b,a,n] = W_out[(6160+a)*128+n] + sum_c agg[b,a,c]*W_out[(16+a*192+c)*128+n]
// ---------------------------------------------------------------------------
__global__ void k3_G(const float* __restrict__ agg,
                     const float* __restrict__ W_out,
                     float* __restrict__ Gp) {
    int t = blockIdx.x * blockDim.x + threadIdx.x;
    int n = t % NOUT;
    int ba = t / NOUT;
    int a = ba % NA;

    const float* ar = agg + (size_t)ba * NC2;
    const float* wr = W_out + (size_t)(NFT + a * NC2) * NOUT + n;
    float acc = W_out[(size_t)(NFT + NA * NC2 + a) * NOUT + n];
#pragma unroll 8
    for (int c = 0; c < NC2; ++c)
        acc = fmaf(ar[c], wr[(size_t)c * NOUT], acc);
    Gp[t] = acc;
}

// ---------------------------------------------------------------------------
// K4: out[b,v,n] = tanh( b_out[n] + sum_k x[b,v,k]*W_out[k*128+n]
//                        + sum_a ew[b,v,a]*Gp[b,a,n] )
// block = (b, 32-row chunk); 256 thr: n = tid&127, rg = tid>>7.
// Thread keeps W_out column (16) + Gp column (32) in REGISTERS, computes
// 16 rows; x/ew rows staged in LDS and read back as wave-broadcast.
// ---------------------------------------------------------------------------
#define K4_ROWS 32
__global__ void k4_out(const float* __restrict__ x,
                       const float* __restrict__ fbuf,
                       const float* __restrict__ Gp,
                       const float* __restrict__ W_out,
                       const float* __restrict__ b_out,
                       float* __restrict__ out) {
    __shared__ float xs[K4_ROWS][NFT];   // 2 KB
    __shared__ float es[K4_ROWS][NA];    // 4 KB

    int b     = blockIdx.x;
    int chunk = blockIdx.y;
    int tid   = threadIdx.x;
    int n  = tid & (NOUT - 1);
    int rg = tid >> 7;                   // 0 or 1

    int rowbase = b * NV + chunk * K4_ROWS;

    // stage x rows (512 floats) and ew rows (1024 floats)
    {
        const float* xsrc = x + (size_t)rowbase * NFT;
#pragma unroll
        for (int l = tid; l < K4_ROWS * NFT; l += 256)
            ((float*)xs)[l] = xsrc[l];
#pragma unroll
        for (int l = tid; l < K4_ROWS * NA; l += 256) {
            int rr = l >> 5, aa = l & 31;
            es[rr][aa] = fbuf[(size_t)(rowbase + rr) * NC + NP + aa];
        }
    }

    // register-resident columns
    float Wc[NFT], Gc[NA];
#pragma unroll
    for (int k = 0; k < NFT; ++k)
        Wc[k] = W_out[(size_t)k * NOUT + n];
    const float* gpb = Gp + ((size_t)b * NA) * NOUT + n;
#pragma unroll
    for (int a = 0; a < NA; ++a)
        Gc[a] = gpb[(size_t)a * NOUT];
    float bn = b_out[n];

    __syncthreads();

    float* orow = out + ((size_t)rowbase + rg * 16) * NOUT + n;
#pragma unroll
    for (int r = 0; r < 16; ++r) {
        int row = rg * 16 + r;
        float s = bn;
#pragma unroll
        for (int k = 0; k < NFT; ++k)
            s = fmaf(xs[row][k], Wc[k], s);
#pragma unroll
        for (int a = 0; a < NA; ++a)
            s = fmaf(es[row][a], Gc[a], s);
        // fast tanh: clamp then (e-1)/(e+1), e = exp(2s)
        s = fminf(fmaxf(s, -15.f), 15.f);
        float e = __expf(2.f * s);
        orow[(size_t)r * NOUT] = (e - 1.f) * __builtin_amdgcn_rcpf(e + 1.f);
    }
}

// ---------------------------------------------------------------------------
extern "C" void kernel_launch(void* const* d_in, const int* in_sizes, int n_in,
                              void* d_out, int out_size, void* d_ws, size_t ws_size,
                              hipStream_t stream) {
    const float* x     = (const float*)d_in[0];
    const float* W_flr = (const float*)d_in[1];
    const float* b_flr = (const float*)d_in[2];
    const float* W_s   = (const float*)d_in[3];
    const float* b_s   = (const float*)d_in[4];
    const float* W_out = (const float*)d_in[5];
    const float* b_out = (const float*)d_in[6];
    float* out = (float*)d_out;

    // workspace layout (floats)
    float* fbuf = (float*)d_ws;                         // B*V*96        = 3,145,728
    float* agg  = fbuf + (size_t)NB * NV * NC;          // B*A*192       =   196,608
    float* Gp   = agg  + (size_t)NB * NA * NC2;         // B*A*128       =   131,072
    float* part = Gp   + (size_t)NB * NA * NOUT;        // 2048*1536     = 3,145,728

    // K1
    {
        int n = NB * NV * NC;
        k1_vertex<<<n / 256, 256, 0, stream>>>(x, W_flr, b_flr, W_s, b_s, fbuf);
    }
    // K2a: grid (B, 4, 16) x 256 = 2048 blocks
    {
        dim3 g(NB, NA / 8, NSPLIT);
        k2_part<<<g, 256, 0, stream>>>(fbuf, part);
    }
    // K2b
    {
        int n = NB * 4 * NPAIR;
        k2_comb<<<n / 256, 256, 0, stream>>>(part, agg);
    }
    // K3
    {
        int n = NB * NA * NOUT;
        k3_G<<<n / 256, 256, 0, stream>>>(agg, W_out, Gp);
    }
    // K4: grid (B, 32) x 256
    {
        dim3 g(NB, NV / K4_ROWS);
        k4_out<<<g, 256, 0, stream>>>(x, fbuf, Gp, W_out, b_out, out);
    }
}

// Round 4
// 42.329 us; speedup vs baseline: 4.4920x; 1.7803x over previous
//
#include <hip/hip_runtime.h>
#include <math.h>

#define NB 32      // B
#define NV 1024    // V
#define NFT 16     // F
#define NA 32      // A
#define NP 64      // P
#define NOUT 128   // NF
#define NC 96      // C = P + A
#define NC2 192    // 2C

#define NSPLIT 16            // V splits
#define VPB 64               // NV/NSPLIT rows per block

// ---------------------------------------------------------------------------
// K2p: fused vertex transform + partial (max,sum) aggregation over a 64-row
// V-slice. grid (B, NSPLIT), 256 threads.
//  phase A (192 thr): f[r][c] = (c<64) ? x@W_flr+b : exp(-(x@W_s+b)^2) -> LDS
//                     (ew part also written to ewbuf for k4)
//  phase B (256 thr): thread owns 4a x 3c tile; per row: 1 float4 broadcast
//                     e-read + 3 b32 f-reads -> 12 products.
// part layout: part[((b*16+vs)*32 + a)*192 + c] = max ; +96+c = sum
// ---------------------------------------------------------------------------
__global__ void k2p(const float* __restrict__ x,
                    const float* __restrict__ W_flr,
                    const float* __restrict__ b_flr,
                    const float* __restrict__ W_s,
                    const float* __restrict__ b_s,
                    float* __restrict__ ewbuf,
                    float* __restrict__ part) {
    __shared__ float xs[VPB][NFT];   // 4 KB
    __shared__ float fs[VPB][NC];    // 24 KB

    int b = blockIdx.x, vs = blockIdx.y, tid = threadIdx.x;
    int rowbase = b * NV + vs * VPB;

    // stage x: 64*16 = 1024 floats = 256 float4
    {
        const float4* xsrc = (const float4*)(x + (size_t)rowbase * NFT);
        ((float4*)xs)[tid] = xsrc[tid];
    }
    __syncthreads();

    // phase A: compute f tile (192 active threads: c = t%96, row-half = t/96)
    if (tid < 192) {
        int c = tid % NC, rh = tid / NC;
        float Wcol[NFT], bias;
        if (c < NP) {
            bias = b_flr[c];
#pragma unroll
            for (int k = 0; k < NFT; ++k) Wcol[k] = W_flr[k * NP + c];
        } else {
            int a = c - NP;
            bias = b_s[a];
#pragma unroll
            for (int k = 0; k < NFT; ++k) Wcol[k] = W_s[k * NA + a];
        }
#pragma unroll
        for (int r0 = 0; r0 < 32; ++r0) {
            int r = rh * 32 + r0;
            float acc = bias;
#pragma unroll
            for (int k = 0; k < NFT; ++k)
                acc = fmaf(xs[r][k], Wcol[k], acc);
            if (c >= NP) {
                acc = __expf(-acc * acc);
                ewbuf[(size_t)(rowbase + r) * NA + (c - NP)] = acc;
            }
            fs[r][c] = acc;
        }
    }
    __syncthreads();

    // phase B: reduction. at = tid>>5 (a-quad), ct = tid&31 (c-triple)
    int at = tid >> 5, ct = tid & 31;
    int cbase = ct * 3;
    float sm[4][3], mx[4][3];
#pragma unroll
    for (int i = 0; i < 4; ++i)
#pragma unroll
        for (int j = 0; j < 3; ++j) { sm[i][j] = 0.f; mx[i][j] = -INFINITY; }

    for (int r = 0; r < VPB; ++r) {
        float4 e4 = *(const float4*)&fs[r][NP + at * 4];
        float f0 = fs[r][cbase], f1 = fs[r][cbase + 1], f2 = fs[r][cbase + 2];
        float ee[4] = {e4.x, e4.y, e4.z, e4.w};
#pragma unroll
        for (int i = 0; i < 4; ++i) {
            float p0 = ee[i] * f0, p1 = ee[i] * f1, p2 = ee[i] * f2;
            sm[i][0] += p0; sm[i][1] += p1; sm[i][2] += p2;
            mx[i][0] = fmaxf(mx[i][0], p0);
            mx[i][1] = fmaxf(mx[i][1], p1);
            mx[i][2] = fmaxf(mx[i][2], p2);
        }
    }

    float* pb = part + (size_t)((b * NSPLIT + vs) * NA) * NC2;
#pragma unroll
    for (int i = 0; i < 4; ++i) {
        int a = at * 4 + i;
#pragma unroll
        for (int j = 0; j < 3; ++j) {
            pb[a * NC2 + cbase + j]      = mx[i][j];
            pb[a * NC2 + NC + cbase + j] = sm[i][j];
        }
    }
}

// ---------------------------------------------------------------------------
// K23: combine NSPLIT partials -> agg row (in LDS) -> G matmul.
// grid (B, A), 192 threads.
// Gp[(b*32+a)*128+n] = W_out[(16+32*192+a)*128+n] + sum_c agg[c]*W_out[(16+a*192+c)*128+n]
// ---------------------------------------------------------------------------
__global__ void k23(const float* __restrict__ part,
                    const float* __restrict__ W_out,
                    float* __restrict__ Gp) {
    __shared__ float aggL[NC2];
    int b = blockIdx.x, a = blockIdx.y, tid = threadIdx.x;

    // combine: thread j<96 does max over vs; j in [96,192) does sum
    {
        const float* pb = part + (size_t)(b * NSPLIT * NA + a) * NC2 + tid;
        const size_t stride = (size_t)NA * NC2;
        if (tid < NC) {
            float m = -INFINITY;
#pragma unroll
            for (int vsi = 0; vsi < NSPLIT; ++vsi)
                m = fmaxf(m, pb[vsi * stride]);
            aggL[tid] = m;
        } else {
            float s = 0.f;
#pragma unroll
            for (int vsi = 0; vsi < NSPLIT; ++vsi)
                s += pb[vsi * stride];
            aggL[tid] = s * (1.0f / (float)NV);
        }
    }
    __syncthreads();

    if (tid < NOUT) {
        int n = tid;
        const float* wr = W_out + (size_t)(NFT + a * NC2) * NOUT + n;
        float acc = W_out[(size_t)(NFT + NA * NC2 + a) * NOUT + n];
#pragma unroll 8
        for (int c = 0; c < NC2; ++c)
            acc = fmaf(aggL[c], wr[(size_t)c * NOUT], acc);
        Gp[(size_t)(b * NA + a) * NOUT + n] = acc;
    }
}

// ---------------------------------------------------------------------------
// K4: out[b,v,n] = tanh( b_out[n] + sum_k x[b,v,k]*W_out[k*128+n]
//                        + sum_a ew[b,v,a]*Gp[b,a,n] )
// block = (b, 32-row chunk); 256 thr: n = tid&127, rg = tid>>7.
// W_out column (16) + Gp column (32) in registers; x/ew staged in LDS.
// ---------------------------------------------------------------------------
#define K4_ROWS 32
__global__ void k4_out(const float* __restrict__ x,
                       const float* __restrict__ ewbuf,
                       const float* __restrict__ Gp,
                       const float* __restrict__ W_out,
                       const float* __restrict__ b_out,
                       float* __restrict__ out) {
    __shared__ float xs[K4_ROWS][NFT];   // 2 KB
    __shared__ float es[K4_ROWS][NA];    // 4 KB

    int b     = blockIdx.x;
    int chunk = blockIdx.y;
    int tid   = threadIdx.x;
    int n  = tid & (NOUT - 1);
    int rg = tid >> 7;                   // 0 or 1

    int rowbase = b * NV + chunk * K4_ROWS;

    // stage: x rows (512 floats = 128 float4), ew rows (1024 floats = 256 float4)
    {
        const float4* esrc = (const float4*)(ewbuf + (size_t)rowbase * NA);
        ((float4*)es)[tid] = esrc[tid];
        if (tid < 128) {
            const float4* xsrc = (const float4*)(x + (size_t)rowbase * NFT);
            ((float4*)xs)[tid] = xsrc[tid];
        }
    }

    // register-resident columns
    float Wc[NFT], Gc[NA];
#pragma unroll
    for (int k = 0; k < NFT; ++k)
        Wc[k] = W_out[(size_t)k * NOUT + n];
    const float* gpb = Gp + ((size_t)b * NA) * NOUT + n;
#pragma unroll
    for (int a = 0; a < NA; ++a)
        Gc[a] = gpb[(size_t)a * NOUT];
    float bn = b_out[n];

    __syncthreads();

    float* orow = out + ((size_t)rowbase + rg * 16) * NOUT + n;
#pragma unroll
    for (int r = 0; r < 16; ++r) {
        int row = rg * 16 + r;
        float s = bn;
#pragma unroll
        for (int k = 0; k < NFT; ++k)
            s = fmaf(xs[row][k], Wc[k], s);
#pragma unroll
        for (int a = 0; a < NA; ++a)
            s = fmaf(es[row][a], Gc[a], s);
        // fast tanh: clamp then (e-1)/(e+1), e = exp(2s)
        s = fminf(fmaxf(s, -15.f), 15.f);
        float e = __expf(2.f * s);
        orow[(size_t)r * NOUT] = (e - 1.f) * __builtin_amdgcn_rcpf(e + 1.f);
    }
}

// ---------------------------------------------------------------------------
extern "C" void kernel_launch(void* const* d_in, const int* in_sizes, int n_in,
                              void* d_out, int out_size, void* d_ws, size_t ws_size,
                              hipStream_t stream) {
    const float* x     = (const float*)d_in[0];
    const float* W_flr = (const float*)d_in[1];
    const float* b_flr = (const float*)d_in[2];
    const float* W_s   = (const float*)d_in[3];
    const float* b_s   = (const float*)d_in[4];
    const float* W_out = (const float*)d_in[5];
    const float* b_out = (const float*)d_in[6];
    float* out = (float*)d_out;

    // workspace layout (floats)
    float* ewbuf = (float*)d_ws;                              // B*V*32        = 1,048,576
    float* part  = ewbuf + (size_t)NB * NV * NA;              // 512*32*192    = 3,145,728
    float* Gp    = part  + (size_t)NB * NSPLIT * NA * NC2;    // B*A*128       =   131,072

    // K2p: grid (B, 16) x 256
    {
        dim3 g(NB, NSPLIT);
        k2p<<<g, 256, 0, stream>>>(x, W_flr, b_flr, W_s, b_s, ewbuf, part);
    }
    // K23: grid (B, A) x 192
    {
        dim3 g(NB, NA);
        k23<<<g, 192, 0, stream>>>(part, W_out, Gp);
    }
    // K4: grid (B, 32) x 256
    {
        dim3 g(NB, NV / K4_ROWS);
        k4_out<<<g, 256, 0, stream>>>(x, ewbuf, Gp, W_out, b_out, out);
    }
}